// Round 6
// baseline (359.765 us; speedup 1.0000x reference)
//
#include <hip/hip_runtime.h>

#define NB_HG 2048   // H*G = 32*64
#define DIM_N 128
#define DIM_D 128

// Numerics: per output element, strictly sequential ascending-d fp32 FMA
// (bit-matches harness golden; verified absmax=0 rounds 4-5).
// LDS layout: Xt[d][n ^ 4*(d&7)] float4-XOR swizzle, conflict-free both ways
// (verified: SQ_LDS_BANK_CONFLICT = 0 in round 5).
// This round: explicit 2-deep register double-buffer (qa/qb, ba/bb) so all
// 8 proj-loads + 8 ds_reads of half-step k+1 are in flight during the 256
// FMAs of half-step k (VGPR 92 -> ~220; removes serialized-load stalls).
__global__ __launch_bounds__(256, 2)
void qjl_sketch_kernel(const float* __restrict__ data,
                       const float* __restrict__ mask,
                       const float* __restrict__ proj,
                       int* __restrict__ out)
{
    __shared__ float Xt[DIM_D * DIM_N];  // 64 KB -> 2 blocks/CU

    const int type = blockIdx.x;   // 0: inlier s<128, 1: inlier s>=128, 2: outlier s<128
    const int hg   = blockIdx.y;
    const int tid  = threadIdx.x;

    // ---------- stage masked, transposed, swizzled X into LDS ----------
    {
        const int   d  = tid & 127;
        const int   nh = tid >> 7;                 // 0 or 1
        const float m  = mask[hg * DIM_D + d];     // exactly 0.0f or 1.0f
        const float w  = (type == 2) ? m : (1.0f - m);
        const float* Xs = data + (size_t)hg * (DIM_N * DIM_D) + d;
        const int   pcs = 4 * (d & 7);
        float* row = &Xt[d * DIM_N];
        #pragma unroll
        for (int g = 0; g < 16; ++g) {
            const int n0 = g * 8 + nh * 4;         // 4-aligned logical n block
            float4 v;
            v.x = Xs[(size_t)(n0 + 0) * DIM_D] * w;   // exact: w in {0,1}
            v.y = Xs[(size_t)(n0 + 1) * DIM_D] * w;
            v.z = Xs[(size_t)(n0 + 2) * DIM_D] * w;
            v.w = Xs[(size_t)(n0 + 3) * DIM_D] * w;
            *reinterpret_cast<float4*>(&row[n0 ^ pcs]) = v;
        }
    }
    __syncthreads();

    // ---------- register-tiled masked GEMM: 8n x 8s per thread ----------
    const int tn = tid & 15;                       // 16 n-groups
    const int ts = tid >> 4;                       // 16 s-groups
    const int C0 = 4 * tn;                         // first chunk base (floats)
    const int s0 = ((type == 1) ? 128 : 0) + ts * 8;

    float acc[8][8];                               // [j: s-bit][i: n-slot]
    #pragma unroll
    for (int j = 0; j < 8; ++j)
        #pragma unroll
        for (int i = 0; i < 8; ++i) acc[j][i] = 0.0f;

    const float* pbase = proj + (size_t)s0 * DIM_D;

    float4 qa[8], qb[8], ba[8], bb[8];             // double-buffered operands

    // load 8 proj float4s (rows s0..s0+7 at columns db..db+3)
    auto LOADB = [&](float4 (&b)[8], int db) {
        const float* pb = pbase + db;
        #pragma unroll
        for (int j = 0; j < 8; ++j)
            b[j] = *reinterpret_cast<const float4*>(pb + j * DIM_D);
    };
    // load 8 LDS float4s for d = db + 4*phase + dd (phase literal -> swizzle folds)
    auto LOADQ = [&](float4 (&q)[8], int db, int phase) {
        #pragma unroll
        for (int dd = 0; dd < 4; ++dd) {
            const int r7 = 4 * phase + dd;                 // == d2 & 7 (compile-time)
            const int d2 = db + r7;
            const float* r = &Xt[d2 * DIM_N + (C0 ^ (4 * r7))];
            q[2 * dd]     = *reinterpret_cast<const float4*>(r);        // n = C0..C0+3
            q[2 * dd + 1] = *reinterpret_cast<const float4*>(r + 64);   // n = 64+C0..
        }
    };
    // 256 FMAs: 4 ascending d, 8 s-rows, 8 n-slots (serial chain per acc)
    auto FMA4 = [&](const float4 (&q)[8], const float4 (&b)[8]) {
        #pragma unroll
        for (int dd = 0; dd < 4; ++dd) {
            #pragma unroll
            for (int j = 0; j < 8; ++j) {
                const float bv = (dd == 0) ? b[j].x : (dd == 1) ? b[j].y
                               : (dd == 2) ? b[j].z : b[j].w;
                acc[j][0] = fmaf(bv, q[2*dd].x,   acc[j][0]);
                acc[j][1] = fmaf(bv, q[2*dd].y,   acc[j][1]);
                acc[j][2] = fmaf(bv, q[2*dd].z,   acc[j][2]);
                acc[j][3] = fmaf(bv, q[2*dd].w,   acc[j][3]);
                acc[j][4] = fmaf(bv, q[2*dd+1].x, acc[j][4]);
                acc[j][5] = fmaf(bv, q[2*dd+1].y, acc[j][5]);
                acc[j][6] = fmaf(bv, q[2*dd+1].z, acc[j][6]);
                acc[j][7] = fmaf(bv, q[2*dd+1].w, acc[j][7]);
            }
        }
    };

    // prologue: first half-step's operands
    LOADQ(qa, 0, 0);
    LOADB(ba, 0);

    for (int db = 0; db < DIM_D; db += 8) {
        LOADQ(qb, db, 1);                          // prefetch d = db+4..db+7
        LOADB(bb, db + 4);
        FMA4(qa, ba);                              // consume d = db..db+3
        if (db + 8 < DIM_D) {
            LOADQ(qa, db + 8, 0);                  // prefetch d = db+8..db+11
            LOADB(ba, db + 8);
        }
        FMA4(qb, bb);                              // consume d = db+4..db+7
    }

    // ---------- sign-pack (bit j = s0+j > 0) and store as int32 ----------
    const size_t inl_total = (size_t)NB_HG * DIM_N * 32;   // 8388608
    #pragma unroll
    for (int i = 0; i < 8; ++i) {
        int byte = 0;
        #pragma unroll
        for (int j = 0; j < 8; ++j)
            if (acc[j][i] > 0.0f) byte |= (1 << j);
        const int n = (i < 4) ? (C0 + i) : (64 + C0 + (i - 4));
        size_t idx;
        if (type == 2)
            idx = inl_total + ((size_t)hg * DIM_N + n) * 16 + ts;
        else
            idx = ((size_t)hg * DIM_N + n) * 32 + (type == 1 ? 16 : 0) + ts;
        out[idx] = byte;
    }
}

extern "C" void kernel_launch(void* const* d_in, const int* in_sizes, int n_in,
                              void* d_out, int out_size, void* d_ws, size_t ws_size,
                              hipStream_t stream) {
    const float* data = (const float*)d_in[0];   // (1,32,64,128,128) fp32
    const float* mask = (const float*)d_in[1];   // (1,32,64,128) fp32, values {0,1}
    const float* proj = (const float*)d_in[2];   // (256,128) fp32
    int* out = (int*)d_out;                      // 8388608 inlier + 4194304 outlier int32

    dim3 grid(3, NB_HG);
    qjl_sketch_kernel<<<grid, 256, 0, stream>>>(data, mask, proj, out);
}